// Round 9
// baseline (276.572 us; speedup 1.0000x reference)
//
#include <hip/hip_runtime.h>
#include <hip/hip_bf16.h>

// GAT layer: B=32, N=1024, IN_F=OUT_F=256, alpha=0.2
//  k1: WhT[b][o][n] = bf16(h @ W^T), MFMA; fused si/sj pre-scaled by log2(e).
//  k3: phase-decoupled fused attention. Round-8 established the ~75us floor of
//      the interleaved {S; barrier; MFMA; barrier} x16 structure is INTRA-BLOCK
//      SERIALIZATION (occupancy-doubling gave only 6%). New structure:
//        phase 1: FULL 64x1024 S tile -> LDS (132 KB, stride-1032 padded),
//                 pure VALU+HBM streaming, zero barriers -> compiler pipelines
//        ONE __syncthreads
//        phase 2: barrier-free PV: 32 K-steps, A from LDS, B straight from
//                 L2-resident whT (each byte read once per wave), 8 MFMA/step.
//      VALU(S) and MFMA(PV) phases are each bulk and internally sync-free.

#define ALPHA 0.2f
#define LOG2E 1.44269504f

typedef __bf16 bf16x8 __attribute__((ext_vector_type(8)));
typedef __bf16 bf16x4 __attribute__((ext_vector_type(4)));
typedef float  f32x4  __attribute__((ext_vector_type(4)));
typedef unsigned long long u64;

// ---------------- k1: Wh = h @ W^T -> whT (bf16) + si/sj ----------------
// grid 512 x 256 thr; block = 64 n-rows x 256 o, K chunks of 64, reg-prefetched.
__global__ __launch_bounds__(256) void k1_gemm1(const float* __restrict__ h,
                                                const float* __restrict__ W,
                                                const float* __restrict__ a_g,
                                                __bf16* __restrict__ whT,
                                                float* __restrict__ si,
                                                float* __restrict__ sj) {
    __shared__ __bf16 hA[64 * 72];
    __shared__ __bf16 hB[256 * 72];   // W tiles; reused as [o][n] out-staging
    __shared__ float  red[512];
    const int t    = threadIdx.x;
    const int r0   = blockIdx.x * 64;
    const int b    = r0 >> 10;
    const int n0   = r0 & 1023;
    const int w    = t >> 6;
    const int l    = t & 63;
    const int ln   = l & 15;
    const int quad = l >> 4;

    f32x4 acc[4][4] = {};
    float4 ha_r[4], wb_r[16];

    #pragma unroll
    for (int it = 0; it < 4; ++it)
        ha_r[it] = *(const float4*)&h[(size_t)(r0 + it * 16 + (t >> 4)) * 256 + (t & 15) * 4];
    #pragma unroll
    for (int it = 0; it < 16; ++it)
        wb_r[it] = *(const float4*)&W[(size_t)(it * 16 + (t >> 4)) * 256 + (t & 15) * 4];

    for (int kc = 0; kc < 4; ++kc) {
        #pragma unroll
        for (int it = 0; it < 4; ++it) {
            const float4 v = ha_r[it];
            bf16x4 pv = {(__bf16)v.x, (__bf16)v.y, (__bf16)v.z, (__bf16)v.w};
            *(bf16x4*)&hA[(it * 16 + (t >> 4)) * 72 + (t & 15) * 4] = pv;
        }
        #pragma unroll
        for (int it = 0; it < 16; ++it) {
            const float4 v = wb_r[it];
            bf16x4 pv = {(__bf16)v.x, (__bf16)v.y, (__bf16)v.z, (__bf16)v.w};
            *(bf16x4*)&hB[(it * 16 + (t >> 4)) * 72 + (t & 15) * 4] = pv;
        }
        __syncthreads();
        if (kc < 3) {
            const int k0 = (kc + 1) * 64;
            #pragma unroll
            for (int it = 0; it < 4; ++it)
                ha_r[it] = *(const float4*)&h[(size_t)(r0 + it * 16 + (t >> 4)) * 256 + k0 + (t & 15) * 4];
            #pragma unroll
            for (int it = 0; it < 16; ++it)
                wb_r[it] = *(const float4*)&W[(size_t)(it * 16 + (t >> 4)) * 256 + k0 + (t & 15) * 4];
        }
        #pragma unroll
        for (int kk = 0; kk < 2; ++kk) {
            bf16x8 af[4], bfr[4];
            #pragma unroll
            for (int ri = 0; ri < 4; ++ri)
                af[ri] = *(const bf16x8*)&hA[(ri * 16 + ln) * 72 + kk * 32 + quad * 8];
            #pragma unroll
            for (int oi = 0; oi < 4; ++oi)
                bfr[oi] = *(const bf16x8*)&hB[(w * 64 + oi * 16 + ln) * 72 + kk * 32 + quad * 8];
            #pragma unroll
            for (int ri = 0; ri < 4; ++ri)
                #pragma unroll
                for (int oi = 0; oi < 4; ++oi)
                    acc[ri][oi] = __builtin_amdgcn_mfma_f32_16x16x32_bf16(
                        af[ri], bfr[oi], acc[ri][oi], 0, 0, 0);
        }
        __syncthreads();
    }

    #pragma unroll
    for (int ri = 0; ri < 4; ++ri) {
        const int n = ri * 16 + quad * 4;
        #pragma unroll
        for (int oi = 0; oi < 4; ++oi) {
            const int o = w * 64 + oi * 16 + ln;
            bf16x4 pv = {(__bf16)acc[ri][oi][0], (__bf16)acc[ri][oi][1],
                         (__bf16)acc[ri][oi][2], (__bf16)acc[ri][oi][3]};
            *(bf16x4*)&hB[o * 72 + n] = pv;
        }
    }
    __syncthreads();

    #pragma unroll
    for (int it = 0; it < 8; ++it) {
        const int o   = w * 64 + it * 8 + (l >> 3);
        const int seg = l & 7;
        const bf16x8 v = *(const bf16x8*)&hB[o * 72 + seg * 8];
        *(bf16x8*)&whT[((size_t)b * 256 + o) * 1024 + n0 + seg * 8] = v;
    }

    {
        float s1 = 0.f, s2 = 0.f;
        #pragma unroll 8
        for (int oi = 0; oi < 64; ++oi) {
            const int o = w * 64 + oi;
            const float v = (float)hB[o * 72 + l];
            s1 += v * a_g[o];
            s2 += v * a_g[256 + o];
        }
        red[w * 64 + l]       = s1;
        red[256 + w * 64 + l] = s2;
    }
    __syncthreads();
    if (t < 64) {
        si[b * 1024 + n0 + t] =
            (red[t] + red[64 + t] + red[128 + t] + red[192 + t]) * LOG2E;
    } else if (t < 128) {
        const int n = t - 64;
        sj[b * 1024 + n0 + n] =
            (red[256 + n] + red[320 + n] + red[384 + n] + red[448 + n]) * LOG2E;
    }
}

// ---------------- k3: phase-decoupled fused attention ----------------
// grid 512 (XCD-chunked), 512 thr (8 waves), 1 block/CU (LDS-limited).
// Thread t: S rows rowg=t>>4 and rowg+32, cols j4*4..+3 per 64-chunk.
// Wave w: PV o-slice [w*32, w*32+32).
// LDS stride 1032 bf16 (2064 B): 16B-aligned for ds_read_b128; row-stride
// 516 dw mod 32 = 4 banks -> 16-lane column read = 2-way conflict (free).

// phase-1 body: S chunk (64 j) for both rows; distance-1 adj/sj prefetch
#define P1_BODY(JC, A0C, A1C, SJC, A0N, A1N, SJN)                              \
  {                                                                            \
    const int j0 = (JC) * 64;                                                  \
    if ((JC) < 15) {                                                           \
      A0N = *(const int4*)&adjb[(size_t)rowg * 1024 + j0 + 64 + j4 * 4];       \
      A1N = *(const int4*)&adjb[(size_t)(rowg + 32) * 1024 + j0 + 64 + j4 * 4];\
      SJN = *(const float4*)&sj_g[bs + j0 + 64 + j4 * 4];                      \
    }                                                                          \
    {                                                                          \
      float e0 = si0 + SJC.x; e0 = fmaxf(e0, ALPHA * e0);                      \
      float e1 = si0 + SJC.y; e1 = fmaxf(e1, ALPHA * e1);                      \
      float e2 = si0 + SJC.z; e2 = fmaxf(e2, ALPHA * e2);                      \
      float e3 = si0 + SJC.w; e3 = fmaxf(e3, ALPHA * e3);                      \
      const float w0 = A0C.x > 0 ? exp2f(e0) : 0.f;                            \
      const float w1 = A0C.y > 0 ? exp2f(e1) : 0.f;                            \
      const float w2 = A0C.z > 0 ? exp2f(e2) : 0.f;                            \
      const float w3 = A0C.w > 0 ? exp2f(e3) : 0.f;                            \
      bf16x4 pv = {(__bf16)w0, (__bf16)w1, (__bf16)w2, (__bf16)w3};            \
      dsum0 += (float)pv[0] + (float)pv[1] + (float)pv[2] + (float)pv[3];      \
      *(bf16x4*)&lds_s[rowg * 1032 + j0 + j4 * 4] = pv;                        \
    }                                                                          \
    {                                                                          \
      float e0 = si1 + SJC.x; e0 = fmaxf(e0, ALPHA * e0);                      \
      float e1 = si1 + SJC.y; e1 = fmaxf(e1, ALPHA * e1);                      \
      float e2 = si1 + SJC.z; e2 = fmaxf(e2, ALPHA * e2);                      \
      float e3 = si1 + SJC.w; e3 = fmaxf(e3, ALPHA * e3);                      \
      const float w0 = A1C.x > 0 ? exp2f(e0) : 0.f;                            \
      const float w1 = A1C.y > 0 ? exp2f(e1) : 0.f;                            \
      const float w2 = A1C.z > 0 ? exp2f(e2) : 0.f;                            \
      const float w3 = A1C.w > 0 ? exp2f(e3) : 0.f;                            \
      bf16x4 pv = {(__bf16)w0, (__bf16)w1, (__bf16)w2, (__bf16)w3};            \
      dsum1 += (float)pv[0] + (float)pv[1] + (float)pv[2] + (float)pv[3];      \
      *(bf16x4*)&lds_s[(rowg + 32) * 1032 + j0 + j4 * 4] = pv;                 \
    }                                                                          \
  }

// phase-2 body: one K=32 step of PV; distance-1 whT prefetch
#define P2_BODY(JS, B0C, B1C, B0N, B1N)                                        \
  {                                                                            \
    const int j0 = (JS) * 32;                                                  \
    if ((JS) < 31) {                                                           \
      B0N = *(const bf16x8*)&whTb[(size_t)(oc + ln) * 1024 + j0 + 32 + quad * 8];      \
      B1N = *(const bf16x8*)&whTb[(size_t)(oc + 16 + ln) * 1024 + j0 + 32 + quad * 8]; \
    }                                                                          \
    bf16x8 af[4];                                                              \
    _Pragma("unroll")                                                          \
    for (int ri = 0; ri < 4; ++ri)                                             \
      af[ri] = *(const bf16x8*)&lds_s[(ri * 16 + ln) * 1032 + j0 + quad * 8];  \
    __builtin_amdgcn_s_setprio(1);                                             \
    _Pragma("unroll")                                                          \
    for (int ri = 0; ri < 4; ++ri) {                                           \
      acc[ri][0] = __builtin_amdgcn_mfma_f32_16x16x32_bf16(af[ri], B0C,        \
                                                           acc[ri][0], 0, 0, 0); \
      acc[ri][1] = __builtin_amdgcn_mfma_f32_16x16x32_bf16(af[ri], B1C,        \
                                                           acc[ri][1], 0, 0, 0); \
    }                                                                          \
    __builtin_amdgcn_s_setprio(0);                                             \
  }

__global__ __launch_bounds__(512) void k3_attn(const int* __restrict__ adj,
                                               const __bf16* __restrict__ whT,
                                               const float* __restrict__ si_g,
                                               const float* __restrict__ sj_g,
                                               float* __restrict__ out) {
    __shared__ __bf16 lds_s[64 * 1032];   // 129 KiB full S tile, padded stride
    __shared__ float  lds_denom[64];
    const int t = threadIdx.x;           // 0..511
    // XCD-chunked swizzle: 512 % 8 == 0 -> bijective; each XCD owns 64
    // consecutive wgids = 4 whole batches, so its whT slice (2 MB) stays in L2.
    const int orig = blockIdx.x;
    const int wgid = (orig & 7) * 64 + (orig >> 3);
    const int b    = wgid >> 4;
    const int i0   = (wgid & 15) << 6;
    const int w    = t >> 6;             // 0..7
    const int l    = t & 63;
    const int ln   = l & 15;
    const int quad = l >> 4;
    const int rowg = t >> 4;             // 0..31 (S row pair: rowg, rowg+32)
    const int j4   = t & 15;             // 0..15
    const int bs   = b * 1024;
    const int oc   = w * 32;             // PV o-slice base

    const float si0 = si_g[bs + i0 + rowg];
    const float si1 = si_g[bs + i0 + rowg + 32];

    float dsum0 = 0.f, dsum1 = 0.f;
    const __bf16* whTb = whT + (size_t)b * 256 * 1024;
    const int*    adjb = adj + ((size_t)(bs + i0)) * 1024;

    // ---- phase 1: full S tile -> LDS (no barriers; compiler pipelines) ----
    int4   a0_c, a1_c, a0_n, a1_n;
    float4 sj_c, sj_n;
    a0_c = *(const int4*)&adjb[(size_t)rowg * 1024 + j4 * 4];
    a1_c = *(const int4*)&adjb[(size_t)(rowg + 32) * 1024 + j4 * 4];
    sj_c = *(const float4*)&sj_g[bs + j4 * 4];

    for (int jj = 0; jj < 8; ++jj) {
        P1_BODY(2 * jj,     a0_c, a1_c, sj_c, a0_n, a1_n, sj_n);
        P1_BODY(2 * jj + 1, a0_n, a1_n, sj_n, a0_c, a1_c, sj_c);
    }

    // denominators: reduce across the 16 j4 lanes of each row
    {
        float v = dsum0;
        v += __shfl_xor(v, 1);
        v += __shfl_xor(v, 2);
        v += __shfl_xor(v, 4);
        v += __shfl_xor(v, 8);
        if (j4 == 0) lds_denom[rowg] = v;
        float u = dsum1;
        u += __shfl_xor(u, 1);
        u += __shfl_xor(u, 2);
        u += __shfl_xor(u, 4);
        u += __shfl_xor(u, 8);
        if (j4 == 0) lds_denom[rowg + 32] = u;
    }

    __syncthreads();   // the kernel's single barrier

    // ---- phase 2: barrier-free PV; B straight from L2-resident whT ----
    f32x4 acc[4][2] = {};
    bf16x8 b0_c, b1_c, b0_n, b1_n;
    b0_c = *(const bf16x8*)&whTb[(size_t)(oc + ln) * 1024 + quad * 8];
    b1_c = *(const bf16x8*)&whTb[(size_t)(oc + 16 + ln) * 1024 + quad * 8];

    for (int ss = 0; ss < 16; ++ss) {
        P2_BODY(2 * ss,     b0_c, b1_c, b0_n, b1_n);
        P2_BODY(2 * ss + 1, b0_n, b1_n, b0_c, b1_c);
    }

    // epilogue: normalize, ELU, store
    #pragma unroll
    for (int ri = 0; ri < 4; ++ri) {
        #pragma unroll
        for (int q = 0; q < 4; ++q) {
            const int il = ri * 16 + quad * 4 + q;
            const float dinv = 1.0f / fmaxf(lds_denom[il], 1e-30f);
            #pragma unroll
            for (int oi = 0; oi < 2; ++oi) {
                const int o = oc + oi * 16 + ln;
                const float v = acc[ri][oi][q] * dinv;
                const float r = v > 0.f ? v : __expf(v) - 1.f;
                out[((size_t)(bs + i0 + il)) * 256 + o] = r;
            }
        }
    }
}

extern "C" void kernel_launch(void* const* d_in, const int* in_sizes, int n_in,
                              void* d_out, int out_size, void* d_ws, size_t ws_size,
                              hipStream_t stream) {
    const float* h   = (const float*)d_in[0];
    const int*   adj = (const int*)d_in[1];
    const float* W   = (const float*)d_in[2];
    const float* a   = (const float*)d_in[3];
    float* out = (float*)d_out;

    __bf16* whT = (__bf16*)d_ws;                              // 16 MiB
    float*  si  = (float*)((char*)d_ws + (size_t)16777216);   // 128 KiB
    float*  sj  = (float*)((char*)d_ws + (size_t)16777216 + 131072);

    k1_gemm1<<<512, 256, 0, stream>>>(h, W, a, whT, si, sj);
    k3_attn<<<512, 512, 0, stream>>>(adj, whT, si, sj, out);
}

// Round 10
// 254.743 us; speedup vs baseline: 1.0857x; 1.0857x over previous
//
#include <hip/hip_runtime.h>
#include <hip/hip_bf16.h>

// GAT layer: B=32, N=1024, IN_F=OUT_F=256, alpha=0.2
//  k1: WhT = bf16(h @ W^T) stored CHUNK-MAJOR: whT2[b][jc=j/32][o][j%32]
//      (each K=32 chunk = contiguous 16 KB block); fused si/sj (pre-scaled
//      by log2 e).
//  k3: fragment-direct fused attention. Rounds 0-9 showed every structure
//      with the S->LDS->barrier->MFMA round trip lands at 75-99us with all
//      pipes <25% busy. This version deletes the round trip:
//      wave w owns rows [i0+w*16,+16) x ALL 256 o, so lane l computes S
//      directly in the MFMA A-fragment layout (row w*16+(l&15), k-slice
//      (l>>4)*8..+7) -> S->MFMA is register-direct, no lds_s, no S-barrier.
//      whT chunks are cooperatively staged to LDS (contiguous 16KB, double-
//      buffered) so each byte is read once per block (r4's mistake avoided).
//      One lgkm-only barrier per chunk (4-wave raw barrier = r3/r5-proven).
//      Per chunk/wave: 16 ds_read_b128 + 16 MFMA (1:1), 8 SVALs, 4 staging
//      loads, distance-2 adj/sj register prefetch.

#define ALPHA 0.2f
#define LOG2E 1.44269504f

typedef __bf16 bf16x8 __attribute__((ext_vector_type(8)));
typedef __bf16 bf16x4 __attribute__((ext_vector_type(4)));
typedef float  f32x4  __attribute__((ext_vector_type(4)));
typedef unsigned long long u64;

// ---------------- k1: Wh = h @ W^T -> whT2 (bf16, chunk-major) + si/sj ------
// grid 512 x 256 thr; block = 64 n-rows x 256 o, K chunks of 64, reg-prefetched.
__global__ __launch_bounds__(256) void k1_gemm1(const float* __restrict__ h,
                                                const float* __restrict__ W,
                                                const float* __restrict__ a_g,
                                                __bf16* __restrict__ whT,
                                                float* __restrict__ si,
                                                float* __restrict__ sj) {
    __shared__ __bf16 hA[64 * 72];
    __shared__ __bf16 hB[256 * 72];   // W tiles; reused as [o][n] out-staging
    __shared__ float  red[512];
    const int t    = threadIdx.x;
    const int r0   = blockIdx.x * 64;
    const int b    = r0 >> 10;
    const int n0   = r0 & 1023;
    const int w    = t >> 6;
    const int l    = t & 63;
    const int ln   = l & 15;
    const int quad = l >> 4;

    f32x4 acc[4][4] = {};
    float4 ha_r[4], wb_r[16];

    #pragma unroll
    for (int it = 0; it < 4; ++it)
        ha_r[it] = *(const float4*)&h[(size_t)(r0 + it * 16 + (t >> 4)) * 256 + (t & 15) * 4];
    #pragma unroll
    for (int it = 0; it < 16; ++it)
        wb_r[it] = *(const float4*)&W[(size_t)(it * 16 + (t >> 4)) * 256 + (t & 15) * 4];

    for (int kc = 0; kc < 4; ++kc) {
        #pragma unroll
        for (int it = 0; it < 4; ++it) {
            const float4 v = ha_r[it];
            bf16x4 pv = {(__bf16)v.x, (__bf16)v.y, (__bf16)v.z, (__bf16)v.w};
            *(bf16x4*)&hA[(it * 16 + (t >> 4)) * 72 + (t & 15) * 4] = pv;
        }
        #pragma unroll
        for (int it = 0; it < 16; ++it) {
            const float4 v = wb_r[it];
            bf16x4 pv = {(__bf16)v.x, (__bf16)v.y, (__bf16)v.z, (__bf16)v.w};
            *(bf16x4*)&hB[(it * 16 + (t >> 4)) * 72 + (t & 15) * 4] = pv;
        }
        __syncthreads();
        if (kc < 3) {
            const int k0 = (kc + 1) * 64;
            #pragma unroll
            for (int it = 0; it < 4; ++it)
                ha_r[it] = *(const float4*)&h[(size_t)(r0 + it * 16 + (t >> 4)) * 256 + k0 + (t & 15) * 4];
            #pragma unroll
            for (int it = 0; it < 16; ++it)
                wb_r[it] = *(const float4*)&W[(size_t)(it * 16 + (t >> 4)) * 256 + k0 + (t & 15) * 4];
        }
        #pragma unroll
        for (int kk = 0; kk < 2; ++kk) {
            bf16x8 af[4], bfr[4];
            #pragma unroll
            for (int ri = 0; ri < 4; ++ri)
                af[ri] = *(const bf16x8*)&hA[(ri * 16 + ln) * 72 + kk * 32 + quad * 8];
            #pragma unroll
            for (int oi = 0; oi < 4; ++oi)
                bfr[oi] = *(const bf16x8*)&hB[(w * 64 + oi * 16 + ln) * 72 + kk * 32 + quad * 8];
            #pragma unroll
            for (int ri = 0; ri < 4; ++ri)
                #pragma unroll
                for (int oi = 0; oi < 4; ++oi)
                    acc[ri][oi] = __builtin_amdgcn_mfma_f32_16x16x32_bf16(
                        af[ri], bfr[oi], acc[ri][oi], 0, 0, 0);
        }
        __syncthreads();
    }

    #pragma unroll
    for (int ri = 0; ri < 4; ++ri) {
        const int n = ri * 16 + quad * 4;
        #pragma unroll
        for (int oi = 0; oi < 4; ++oi) {
            const int o = w * 64 + oi * 16 + ln;
            bf16x4 pv = {(__bf16)acc[ri][oi][0], (__bf16)acc[ri][oi][1],
                         (__bf16)acc[ri][oi][2], (__bf16)acc[ri][oi][3]};
            *(bf16x4*)&hB[o * 72 + n] = pv;
        }
    }
    __syncthreads();

    // whT2 writes: chunk-major [b][j/32][o][j%32]
    #pragma unroll
    for (int it = 0; it < 8; ++it) {
        const int o   = w * 64 + it * 8 + (l >> 3);
        const int seg = l & 7;
        const bf16x8 v = *(const bf16x8*)&hB[o * 72 + seg * 8];
        const int j   = n0 + seg * 8;
        *(bf16x8*)&whT[(((size_t)b * 32 + (j >> 5)) * 256 + o) * 32 + (j & 31)] = v;
    }

    {
        float s1 = 0.f, s2 = 0.f;
        #pragma unroll 8
        for (int oi = 0; oi < 64; ++oi) {
            const int o = w * 64 + oi;
            const float v = (float)hB[o * 72 + l];
            s1 += v * a_g[o];
            s2 += v * a_g[256 + o];
        }
        red[w * 64 + l]       = s1;
        red[256 + w * 64 + l] = s2;
    }
    __syncthreads();
    if (t < 64) {
        si[b * 1024 + n0 + t] =
            (red[t] + red[64 + t] + red[128 + t] + red[192 + t]) * LOG2E;
    } else if (t < 128) {
        const int n = t - 64;
        sj[b * 1024 + n0 + n] =
            (red[256 + n] + red[320 + n] + red[384 + n] + red[448 + n]) * LOG2E;
    }
}

// ---------------- k3: fragment-direct fused attention ----------------
// grid 512 (XCD-chunked), 256 thr (4 waves). 32 chunks of K=32.
// Wave w: rows [i0+w*16,+16) x 256 o. Lane l: S row w*16+(l&15),
// k-slice (l>>4)*8..+7 == the MFMA A-fragment layout.
#define SVAL(SI, SJE, AV) \
    ({ float _e = (SI) + (SJE); _e = fmaxf(_e, ALPHA * _e); \
       (AV) > 0 ? exp2f(_e) : 0.f; })

#define K3_CHUNK(C, BUFR, BUFW, AP0, AP1, SJ0, SJ1)                            \
  {                                                                            \
    const int c_ = (C);                                                        \
    /* 1. stage chunk c+1 -> vs (contiguous 16KB, 16B/lane coalesced) */       \
    if (c_ < 31) {                                                             \
      const __bf16* src = whTb + (size_t)(c_ + 1) * 8192;                      \
      _Pragma("unroll")                                                        \
      for (int p = 0; p < 4; ++p)                                              \
        vs[p] = *(const bf16x8*)&src[p * 2048 + t * 8];                        \
    }                                                                          \
    /* 2. S fragment: register-direct A-operand (no LDS round trip) */         \
    bf16x8 af;                                                                 \
    af[0] = (__bf16)SVAL(si0, SJ0.x, AP0.x);                                   \
    af[1] = (__bf16)SVAL(si0, SJ0.y, AP0.y);                                   \
    af[2] = (__bf16)SVAL(si0, SJ0.z, AP0.z);                                   \
    af[3] = (__bf16)SVAL(si0, SJ0.w, AP0.w);                                   \
    af[4] = (__bf16)SVAL(si0, SJ1.x, AP1.x);                                   \
    af[5] = (__bf16)SVAL(si0, SJ1.y, AP1.y);                                   \
    af[6] = (__bf16)SVAL(si0, SJ1.z, AP1.z);                                   \
    af[7] = (__bf16)SVAL(si0, SJ1.w, AP1.w);                                   \
    dsum += (float)af[0] + (float)af[1] + (float)af[2] + (float)af[3]          \
          + (float)af[4] + (float)af[5] + (float)af[6] + (float)af[7];         \
    /* 3. reload adj/sj with chunk c+2 (distance-2, period-2 rotation) */      \
    if (c_ + 2 < 32) {                                                         \
      const int jr = (c_ + 2) * 32 + quad * 8;                                 \
      AP0 = *(const int4*)&adjb[arow + jr];                                    \
      AP1 = *(const int4*)&adjb[arow + jr + 4];                                \
      SJ0 = *(const float4*)&sjb[jr];                                          \
      SJ1 = *(const float4*)&sjb[jr + 4];                                      \
    }                                                                          \
    /* 4. PV: 16 x {ds_read_b128, MFMA} (1:1 density) */                       \
    __builtin_amdgcn_s_setprio(1);                                             \
    _Pragma("unroll")                                                          \
    for (int oi = 0; oi < 16; ++oi) {                                          \
      const bf16x8 bfr = *(const bf16x8*)&BUFR[(oi * 16 + ln) * 32 + quad * 8];\
      acc[oi] = __builtin_amdgcn_mfma_f32_16x16x32_bf16(af, bfr, acc[oi],      \
                                                        0, 0, 0);              \
    }                                                                          \
    __builtin_amdgcn_s_setprio(0);                                             \
    /* 5. commit staged chunk c+1 to the other buffer */                       \
    if (c_ < 31) {                                                             \
      _Pragma("unroll")                                                        \
      for (int p = 0; p < 4; ++p)                                              \
        *(bf16x8*)&BUFW[p * 2048 + t * 8] = vs[p];                             \
    }                                                                          \
    /* 6. lgkm-only barrier: ds_writes visible; global loads (adj c+2) stay */ \
    /* in flight across it with compiler-counted vmcnt (T4) */                 \
    asm volatile("s_waitcnt lgkmcnt(0)" ::: "memory");                         \
    __builtin_amdgcn_s_barrier();                                              \
  }

__global__ __launch_bounds__(256) void k3_attn(const int* __restrict__ adj,
                                               const __bf16* __restrict__ whT,
                                               const float* __restrict__ si_g,
                                               const float* __restrict__ sj_g,
                                               float* __restrict__ out) {
    __shared__ __bf16 bufA[8192];   // 16 KB whT chunk [o=256][j=32]
    __shared__ __bf16 bufB[8192];
    __shared__ float  lds_denom[64];
    const int t = threadIdx.x;      // 0..255
    // XCD-chunked swizzle: 512 % 8 == 0 -> bijective; each XCD owns 64
    // consecutive wgids = 4 whole batches, so its whT slice (2 MB) stays in L2.
    const int orig = blockIdx.x;
    const int wgid = (orig & 7) * 64 + (orig >> 3);
    const int b    = wgid >> 4;
    const int i0   = (wgid & 15) << 6;
    const int w    = t >> 6;        // 0..3: wave row-block
    const int l    = t & 63;
    const int ln   = l & 15;
    const int quad = l >> 4;
    const int bs   = b * 1024;

    const __bf16* whTb = whT + (size_t)b * 32 * 8192;
    const int*    adjb = adj + ((size_t)(bs + i0)) * 1024;
    const float*  sjb  = sj_g + bs;
    const size_t  arow = (size_t)(w * 16 + ln) * 1024;

    const float si0 = si_g[bs + i0 + w * 16 + ln];   // one row scalar per lane

    float dsum = 0.f;
    f32x4 acc[16] = {};
    bf16x8 vs[4];

    // prologue: chunk 0 -> bufA; adj/sj for chunks 0 and 1
    #pragma unroll
    for (int p = 0; p < 4; ++p)
        vs[p] = *(const bf16x8*)&whTb[p * 2048 + t * 8];
    #pragma unroll
    for (int p = 0; p < 4; ++p)
        *(bf16x8*)&bufA[p * 2048 + t * 8] = vs[p];

    int4   a00, a01, a10, a11;
    float4 s00, s01, s10, s11;
    a00 = *(const int4*)&adjb[arow + quad * 8];
    a01 = *(const int4*)&adjb[arow + quad * 8 + 4];
    s00 = *(const float4*)&sjb[quad * 8];
    s01 = *(const float4*)&sjb[quad * 8 + 4];
    a10 = *(const int4*)&adjb[arow + 32 + quad * 8];
    a11 = *(const int4*)&adjb[arow + 32 + quad * 8 + 4];
    s10 = *(const float4*)&sjb[32 + quad * 8];
    s11 = *(const float4*)&sjb[32 + quad * 8 + 4];
    __syncthreads();

    for (int cc = 0; cc < 16; ++cc) {
        K3_CHUNK(2 * cc,     bufA, bufB, a00, a01, s00, s01);
        K3_CHUNK(2 * cc + 1, bufB, bufA, a10, a11, s10, s11);
    }

    // denominator: sum the 4 quad partials of each row
    float d = dsum;
    d += __shfl_xor(d, 16);
    d += __shfl_xor(d, 32);
    if (l < 16) lds_denom[w * 16 + l] = d;
    __syncthreads();

    // epilogue: normalize, ELU, store. C/D: row = quad*4+q, col = oi*16+ln.
    #pragma unroll
    for (int q = 0; q < 4; ++q) {
        const int row  = w * 16 + quad * 4 + q;
        const float dinv = 1.0f / fmaxf(lds_denom[row], 1e-30f);
        #pragma unroll
        for (int oi = 0; oi < 16; ++oi) {
            const float v = acc[oi][q] * dinv;
            const float r = v > 0.f ? v : __expf(v) - 1.f;
            out[((size_t)(bs + i0 + row)) * 256 + oi * 16 + ln] = r;
        }
    }
}

extern "C" void kernel_launch(void* const* d_in, const int* in_sizes, int n_in,
                              void* d_out, int out_size, void* d_ws, size_t ws_size,
                              hipStream_t stream) {
    const float* h   = (const float*)d_in[0];
    const int*   adj = (const int*)d_in[1];
    const float* W   = (const float*)d_in[2];
    const float* a   = (const float*)d_in[3];
    float* out = (float*)d_out;

    __bf16* whT = (__bf16*)d_ws;                              // 16 MiB
    float*  si  = (float*)((char*)d_ws + (size_t)16777216);   // 128 KiB
    float*  sj  = (float*)((char*)d_ws + (size_t)16777216 + 131072);

    k1_gemm1<<<512, 256, 0, stream>>>(h, W, a, whT, si, sj);
    k3_attn<<<512, 256, 0, stream>>>(adj, whT, si, sj, out);
}

// Round 12
// 253.137 us; speedup vs baseline: 1.0926x; 1.0063x over previous
//
#include <hip/hip_runtime.h>
#include <hip/hip_bf16.h>

// GAT layer: B=32, N=1024, IN_F=OUT_F=256, alpha=0.2
//  k1: WhT[b][o][n] = bf16(h @ W^T), MFMA; fused si/sj pre-scaled by log2(e).
//  k3: fused adj-read + masked-softmax attention + PV MFMA + ELU.
//      r8 base (8 waves / 512 thr, stride-72 LDS, __syncthreads, 2 blocks/CU)
//      with the S-phase software-pipelined ONE chunk ahead, minimal-diff:
//      commit phase = pure ds_writes (whT chunk c + S frags of chunk c, both
//      already in registers); compute phase co-schedules
//      {whT-stage(c+1) | SVAL(c+1) | adj-load(c+2) | MFMA(c)} between one
//      barrier pair -- VMEM, VALU and MFMA pipes fed simultaneously.
//      Distance-2 adj/sj prefetch via r8's proven c/n register rotation.

#define ALPHA 0.2f
#define LOG2E 1.44269504f

typedef __bf16 bf16x8 __attribute__((ext_vector_type(8)));
typedef __bf16 bf16x4 __attribute__((ext_vector_type(4)));
typedef float  f32x4  __attribute__((ext_vector_type(4)));
typedef unsigned long long u64;

// ---------------- k1: Wh = h @ W^T -> whT (bf16) + si/sj ----------------
// grid 512 x 256 thr; block = 64 n-rows x 256 o, K chunks of 64, reg-prefetched.
__global__ __launch_bounds__(256) void k1_gemm1(const float* __restrict__ h,
                                                const float* __restrict__ W,
                                                const float* __restrict__ a_g,
                                                __bf16* __restrict__ whT,
                                                float* __restrict__ si,
                                                float* __restrict__ sj) {
    __shared__ __bf16 hA[64 * 72];
    __shared__ __bf16 hB[256 * 72];   // W tiles; reused as [o][n] out-staging
    __shared__ float  red[512];
    const int t    = threadIdx.x;
    const int r0   = blockIdx.x * 64;
    const int b    = r0 >> 10;
    const int n0   = r0 & 1023;
    const int w    = t >> 6;
    const int l    = t & 63;
    const int ln   = l & 15;
    const int quad = l >> 4;

    f32x4 acc[4][4] = {};
    float4 ha_r[4], wb_r[16];

    #pragma unroll
    for (int it = 0; it < 4; ++it)
        ha_r[it] = *(const float4*)&h[(size_t)(r0 + it * 16 + (t >> 4)) * 256 + (t & 15) * 4];
    #pragma unroll
    for (int it = 0; it < 16; ++it)
        wb_r[it] = *(const float4*)&W[(size_t)(it * 16 + (t >> 4)) * 256 + (t & 15) * 4];

    for (int kc = 0; kc < 4; ++kc) {
        #pragma unroll
        for (int it = 0; it < 4; ++it) {
            const float4 v = ha_r[it];
            bf16x4 pv = {(__bf16)v.x, (__bf16)v.y, (__bf16)v.z, (__bf16)v.w};
            *(bf16x4*)&hA[(it * 16 + (t >> 4)) * 72 + (t & 15) * 4] = pv;
        }
        #pragma unroll
        for (int it = 0; it < 16; ++it) {
            const float4 v = wb_r[it];
            bf16x4 pv = {(__bf16)v.x, (__bf16)v.y, (__bf16)v.z, (__bf16)v.w};
            *(bf16x4*)&hB[(it * 16 + (t >> 4)) * 72 + (t & 15) * 4] = pv;
        }
        __syncthreads();
        if (kc < 3) {
            const int k0 = (kc + 1) * 64;
            #pragma unroll
            for (int it = 0; it < 4; ++it)
                ha_r[it] = *(const float4*)&h[(size_t)(r0 + it * 16 + (t >> 4)) * 256 + k0 + (t & 15) * 4];
            #pragma unroll
            for (int it = 0; it < 16; ++it)
                wb_r[it] = *(const float4*)&W[(size_t)(it * 16 + (t >> 4)) * 256 + k0 + (t & 15) * 4];
        }
        #pragma unroll
        for (int kk = 0; kk < 2; ++kk) {
            bf16x8 af[4], bfr[4];
            #pragma unroll
            for (int ri = 0; ri < 4; ++ri)
                af[ri] = *(const bf16x8*)&hA[(ri * 16 + ln) * 72 + kk * 32 + quad * 8];
            #pragma unroll
            for (int oi = 0; oi < 4; ++oi)
                bfr[oi] = *(const bf16x8*)&hB[(w * 64 + oi * 16 + ln) * 72 + kk * 32 + quad * 8];
            #pragma unroll
            for (int ri = 0; ri < 4; ++ri)
                #pragma unroll
                for (int oi = 0; oi < 4; ++oi)
                    acc[ri][oi] = __builtin_amdgcn_mfma_f32_16x16x32_bf16(
                        af[ri], bfr[oi], acc[ri][oi], 0, 0, 0);
        }
        __syncthreads();
    }

    #pragma unroll
    for (int ri = 0; ri < 4; ++ri) {
        const int n = ri * 16 + quad * 4;
        #pragma unroll
        for (int oi = 0; oi < 4; ++oi) {
            const int o = w * 64 + oi * 16 + ln;
            bf16x4 pv = {(__bf16)acc[ri][oi][0], (__bf16)acc[ri][oi][1],
                         (__bf16)acc[ri][oi][2], (__bf16)acc[ri][oi][3]};
            *(bf16x4*)&hB[o * 72 + n] = pv;
        }
    }
    __syncthreads();

    #pragma unroll
    for (int it = 0; it < 8; ++it) {
        const int o   = w * 64 + it * 8 + (l >> 3);
        const int seg = l & 7;
        const bf16x8 v = *(const bf16x8*)&hB[o * 72 + seg * 8];
        *(bf16x8*)&whT[((size_t)b * 256 + o) * 1024 + n0 + seg * 8] = v;
    }

    {
        float s1 = 0.f, s2 = 0.f;
        #pragma unroll 8
        for (int oi = 0; oi < 64; ++oi) {
            const int o = w * 64 + oi;
            const float v = (float)hB[o * 72 + l];
            s1 += v * a_g[o];
            s2 += v * a_g[256 + o];
        }
        red[w * 64 + l]       = s1;
        red[256 + w * 64 + l] = s2;
    }
    __syncthreads();
    if (t < 64) {
        si[b * 1024 + n0 + t] =
            (red[t] + red[64 + t] + red[128 + t] + red[192 + t]) * LOG2E;
    } else if (t < 128) {
        const int n = t - 64;
        sj[b * 1024 + n0 + n] =
            (red[256 + n] + red[320 + n] + red[384 + n] + red[448 + n]) * LOG2E;
    }
}

// ---------------- k3: fused attention, S software-pipelined 1 ahead ---------
// grid 512 (XCD-chunked), 512 thr (8 waves). 16 j-chunks of 64.
// Wave w: o-slice [w*32,+32). Thread t: S rows rowg=t>>4, rowg+32; cols j4*4..+3.
// Register rotation (period 2): even ITER consumes adj-c (chunk C+1), loads
// adj-n (chunk C+2); odd ITER vice versa. pvA/pvB alternate as the S frags.

// SVAL for one (adj int4 pair, sj float4) -> two packed bf16x4 + denom accum
#define SVAL_PAIR(PN0, PN1, A0, A1, SJ)                                        \
  {                                                                            \
    float e0 = si0 + SJ.x; e0 = fmaxf(e0, ALPHA * e0);                         \
    float e1 = si0 + SJ.y; e1 = fmaxf(e1, ALPHA * e1);                         \
    float e2 = si0 + SJ.z; e2 = fmaxf(e2, ALPHA * e2);                         \
    float e3 = si0 + SJ.w; e3 = fmaxf(e3, ALPHA * e3);                         \
    const float w0 = A0.x > 0 ? exp2f(e0) : 0.f;                               \
    const float w1 = A0.y > 0 ? exp2f(e1) : 0.f;                               \
    const float w2 = A0.z > 0 ? exp2f(e2) : 0.f;                               \
    const float w3 = A0.w > 0 ? exp2f(e3) : 0.f;                               \
    PN0 = (bf16x4){(__bf16)w0, (__bf16)w1, (__bf16)w2, (__bf16)w3};            \
    dsum0 += (float)PN0[0] + (float)PN0[1] + (float)PN0[2] + (float)PN0[3];    \
    float f0 = si1 + SJ.x; f0 = fmaxf(f0, ALPHA * f0);                         \
    float f1 = si1 + SJ.y; f1 = fmaxf(f1, ALPHA * f1);                         \
    float f2 = si1 + SJ.z; f2 = fmaxf(f2, ALPHA * f2);                         \
    float f3 = si1 + SJ.w; f3 = fmaxf(f3, ALPHA * f3);                         \
    const float u0 = A1.x > 0 ? exp2f(f0) : 0.f;                               \
    const float u1 = A1.y > 0 ? exp2f(f1) : 0.f;                               \
    const float u2 = A1.z > 0 ? exp2f(f2) : 0.f;                               \
    const float u3 = A1.w > 0 ? exp2f(f3) : 0.f;                               \
    PN1 = (bf16x4){(__bf16)u0, (__bf16)u1, (__bf16)u2, (__bf16)u3};            \
    dsum1 += (float)PN1[0] + (float)PN1[1] + (float)PN1[2] + (float)PN1[3];    \
  }

#define K3_ITER(C, PC0, PC1, PN0, PN1, AC0, AC1, SJC, AN0, AN1, SJN)           \
  {                                                                            \
    const int j0 = (C) * 64;                                                   \
    /* commit phase: pure ds_writes (whT chunk C + S frags of chunk C) */      \
    _Pragma("unroll")                                                          \
    for (int it = 0; it < 4; ++it)                                             \
      *(bf16x8*)&lds_w[(it * 64 + (t >> 3)) * 72 + (t & 7) * 8] = vreg[it];    \
    *(bf16x4*)&lds_s[rowg * 72 + j4 * 4] = PC0;                                \
    *(bf16x4*)&lds_s[(rowg + 32) * 72 + j4 * 4] = PC1;                         \
    __syncthreads();                                                           \
    /* compute phase: stage(C+1) | SVAL(C+1) | adj load (C+2) | MFMA(C) */     \
    if ((C) < 15) {                                                            \
      _Pragma("unroll")                                                        \
      for (int it = 0; it < 4; ++it)                                           \
        vreg[it] = *(const bf16x8*)&whTb[                                      \
            (size_t)(it * 64 + (t >> 3)) * 1024 + j0 + 64 + (t & 7) * 8];      \
      SVAL_PAIR(PN0, PN1, AC0, AC1, SJC);                                      \
      if ((C) < 14) {                                                          \
        const int jr = j0 + 128 + j4 * 4;                                      \
        AN0 = *(const int4*)&adjb[(size_t)rowg * 1024 + jr];                   \
        AN1 = *(const int4*)&adjb[(size_t)(rowg + 32) * 1024 + jr];            \
        SJN = *(const float4*)&sj_g[bs + jr];                                  \
      }                                                                        \
    }                                                                          \
    __builtin_amdgcn_s_setprio(1);                                             \
    _Pragma("unroll")                                                          \
    for (int kk = 0; kk < 2; ++kk) {                                           \
      bf16x8 af[4], bfr[2];                                                    \
      _Pragma("unroll")                                                        \
      for (int ri = 0; ri < 4; ++ri)                                           \
        af[ri] = *(const bf16x8*)&lds_s[(ri * 16 + ln) * 72 + kk * 32 + quad * 8]; \
      _Pragma("unroll")                                                        \
      for (int oi = 0; oi < 2; ++oi)                                           \
        bfr[oi] = *(const bf16x8*)&lds_w[(w * 32 + oi * 16 + ln) * 72 + kk * 32 + quad * 8]; \
      _Pragma("unroll")                                                        \
      for (int ri = 0; ri < 4; ++ri)                                           \
        _Pragma("unroll")                                                      \
        for (int oi = 0; oi < 2; ++oi)                                         \
          acc[ri][oi] = __builtin_amdgcn_mfma_f32_16x16x32_bf16(               \
              af[ri], bfr[oi], acc[ri][oi], 0, 0, 0);                          \
    }                                                                          \
    __builtin_amdgcn_s_setprio(0);                                             \
    __syncthreads();                                                           \
  }

__global__ __launch_bounds__(512, 4) void k3_attn(const int* __restrict__ adj,
                                                  const __bf16* __restrict__ whT,
                                                  const float* __restrict__ si_g,
                                                  const float* __restrict__ sj_g,
                                                  float* __restrict__ out) {
    __shared__ __bf16 lds_w[256 * 72];   // 36 KB whT chunk [o][j_local]
    __shared__ __bf16 lds_s[64 * 72];    // 9 KB S tile
    __shared__ float  lds_denom[64];
    const int t = threadIdx.x;           // 0..511
    // XCD-chunked swizzle: 512 % 8 == 0 -> bijective; each XCD owns 64
    // consecutive wgids = 4 whole batches, so its whT slice (2 MB) stays in L2.
    const int orig = blockIdx.x;
    const int wgid = (orig & 7) * 64 + (orig >> 3);
    const int b    = wgid >> 4;
    const int i0   = (wgid & 15) << 6;
    const int w    = t >> 6;             // 0..7
    const int l    = t & 63;
    const int ln   = l & 15;
    const int quad = l >> 4;
    const int rowg = t >> 4;             // 0..31 (S row pair: rowg, rowg+32)
    const int j4   = t & 15;             // 0..15
    const int bs   = b * 1024;

    const float si0 = si_g[bs + i0 + rowg];
    const float si1 = si_g[bs + i0 + rowg + 32];

    float dsum0 = 0.f, dsum1 = 0.f;
    f32x4 acc[4][2] = {};
    const __bf16* whTb = whT + (size_t)b * 256 * 1024;
    const int*    adjb = adj + ((size_t)(bs + i0)) * 1024;

    // staging + pipeline registers (static names, period-2 rotation)
    bf16x8 vreg[4];
    bf16x4 pvA0, pvA1, pvB0, pvB1;       // S fragments (alternating)
    int4   a0_c, a1_c, a0_n, a1_n;       // adj prefetch (c/n rotation)
    float4 sj_c, sj_n;

    // prologue: whT chunk 0 -> vreg; SVAL(0) -> pvA (from adj chunk 0);
    // adj chunk 1 -> the c-set (consumed by ITER(0)'s SVAL(1)).
    #pragma unroll
    for (int it = 0; it < 4; ++it)
        vreg[it] = *(const bf16x8*)&whTb[(size_t)(it * 64 + (t >> 3)) * 1024 + (t & 7) * 8];
    a0_c = *(const int4*)&adjb[(size_t)rowg * 1024 + j4 * 4];
    a1_c = *(const int4*)&adjb[(size_t)(rowg + 32) * 1024 + j4 * 4];
    sj_c = *(const float4*)&sj_g[bs + j4 * 4];
    SVAL_PAIR(pvA0, pvA1, a0_c, a1_c, sj_c);
    a0_c = *(const int4*)&adjb[(size_t)rowg * 1024 + 64 + j4 * 4];
    a1_c = *(const int4*)&adjb[(size_t)(rowg + 32) * 1024 + 64 + j4 * 4];
    sj_c = *(const float4*)&sj_g[bs + 64 + j4 * 4];

    for (int jj = 0; jj < 8; ++jj) {
        // even C: commit pvA; SVAL(C+1) from c-set -> pvB; load C+2 -> n-set
        K3_ITER(2 * jj,     pvA0, pvA1, pvB0, pvB1,
                            a0_c, a1_c, sj_c, a0_n, a1_n, sj_n);
        // odd C: commit pvB; SVAL(C+1) from n-set -> pvA; load C+2 -> c-set
        K3_ITER(2 * jj + 1, pvB0, pvB1, pvA0, pvA1,
                            a0_n, a1_n, sj_n, a0_c, a1_c, sj_c);
    }

    // reduce denominators across the 16 j4 lanes per row
    {
        float v = dsum0;
        v += __shfl_xor(v, 1);
        v += __shfl_xor(v, 2);
        v += __shfl_xor(v, 4);
        v += __shfl_xor(v, 8);
        if (j4 == 0) lds_denom[rowg] = v;
        float u = dsum1;
        u += __shfl_xor(u, 1);
        u += __shfl_xor(u, 2);
        u += __shfl_xor(u, 4);
        u += __shfl_xor(u, 8);
        if (j4 == 0) lds_denom[rowg + 32] = u;
    }
    __syncthreads();
    // epilogue: normalize, ELU, store
    #pragma unroll
    for (int ri = 0; ri < 4; ++ri) {
        #pragma unroll
        for (int q = 0; q < 4; ++q) {
            const int il = ri * 16 + quad * 4 + q;
            const float dinv = 1.0f / fmaxf(lds_denom[il], 1e-30f);
            #pragma unroll
            for (int oi = 0; oi < 2; ++oi) {
                const int o = w * 32 + oi * 16 + ln;
                const float v = acc[ri][oi][q] * dinv;
                const float r = v > 0.f ? v : __expf(v) - 1.f;
                out[((size_t)(bs + i0 + il)) * 256 + o] = r;
            }
        }
    }
}

extern "C" void kernel_launch(void* const* d_in, const int* in_sizes, int n_in,
                              void* d_out, int out_size, void* d_ws, size_t ws_size,
                              hipStream_t stream) {
    const float* h   = (const float*)d_in[0];
    const int*   adj = (const int*)d_in[1];
    const float* W   = (const float*)d_in[2];
    const float* a   = (const float*)d_in[3];
    float* out = (float*)d_out;

    __bf16* whT = (__bf16*)d_ws;                              // 16 MiB
    float*  si  = (float*)((char*)d_ws + (size_t)16777216);   // 128 KiB
    float*  sj  = (float*)((char*)d_ws + (size_t)16777216 + 131072);

    k1_gemm1<<<512, 256, 0, stream>>>(h, W, a, whT, si, sj);
    k3_attn<<<512, 512, 0, stream>>>(adj, whT, si, sj, out);
}

// Round 13
// 251.487 us; speedup vs baseline: 1.0997x; 1.0066x over previous
//
#include <hip/hip_runtime.h>
#include <hip/hip_bf16.h>

// GAT layer: B=32, N=1024, IN_F=OUT_F=256, alpha=0.2
//  k1: WhT[b][o][n] = bf16(h @ W^T), MFMA; fused si/sj pre-scaled by log2(e).
//  k3: fused adj-read + masked-softmax attention + PV MFMA + ELU.
//      r8 dataflow widened to 1024 thr / 16 waves per block: wave w owns a
//      16-wide o-slice, thread t owns ONE S row (rowg=t>>4). Per-block
//      staging/adj/barrier cost unchanged; per-wave state halves ->
//      VGPR <= 64 (__launch_bounds__(1024,8)) so 2 blocks x 16 waves =
//      32 waves/CU = 100% occupancy (the grid caps blocks/CU at 2; more
//      waves per block is the only TLP lever left - r12 taught that the
//      512-block grid, not resources, was the occupancy bound all along).

#define ALPHA 0.2f
#define LOG2E 1.44269504f

typedef __bf16 bf16x8 __attribute__((ext_vector_type(8)));
typedef __bf16 bf16x4 __attribute__((ext_vector_type(4)));
typedef float  f32x4  __attribute__((ext_vector_type(4)));
typedef unsigned long long u64;

// ---------------- k1: Wh = h @ W^T -> whT (bf16) + si/sj ----------------
// grid 512 x 256 thr; block = 64 n-rows x 256 o, K chunks of 64, reg-prefetched.
__global__ __launch_bounds__(256) void k1_gemm1(const float* __restrict__ h,
                                                const float* __restrict__ W,
                                                const float* __restrict__ a_g,
                                                __bf16* __restrict__ whT,
                                                float* __restrict__ si,
                                                float* __restrict__ sj) {
    __shared__ __bf16 hA[64 * 72];
    __shared__ __bf16 hB[256 * 72];   // W tiles; reused as [o][n] out-staging
    __shared__ float  red[512];
    const int t    = threadIdx.x;
    const int r0   = blockIdx.x * 64;
    const int b    = r0 >> 10;
    const int n0   = r0 & 1023;
    const int w    = t >> 6;
    const int l    = t & 63;
    const int ln   = l & 15;
    const int quad = l >> 4;

    f32x4 acc[4][4] = {};
    float4 ha_r[4], wb_r[16];

    #pragma unroll
    for (int it = 0; it < 4; ++it)
        ha_r[it] = *(const float4*)&h[(size_t)(r0 + it * 16 + (t >> 4)) * 256 + (t & 15) * 4];
    #pragma unroll
    for (int it = 0; it < 16; ++it)
        wb_r[it] = *(const float4*)&W[(size_t)(it * 16 + (t >> 4)) * 256 + (t & 15) * 4];

    for (int kc = 0; kc < 4; ++kc) {
        #pragma unroll
        for (int it = 0; it < 4; ++it) {
            const float4 v = ha_r[it];
            bf16x4 pv = {(__bf16)v.x, (__bf16)v.y, (__bf16)v.z, (__bf16)v.w};
            *(bf16x4*)&hA[(it * 16 + (t >> 4)) * 72 + (t & 15) * 4] = pv;
        }
        #pragma unroll
        for (int it = 0; it < 16; ++it) {
            const float4 v = wb_r[it];
            bf16x4 pv = {(__bf16)v.x, (__bf16)v.y, (__bf16)v.z, (__bf16)v.w};
            *(bf16x4*)&hB[(it * 16 + (t >> 4)) * 72 + (t & 15) * 4] = pv;
        }
        __syncthreads();
        if (kc < 3) {
            const int k0 = (kc + 1) * 64;
            #pragma unroll
            for (int it = 0; it < 4; ++it)
                ha_r[it] = *(const float4*)&h[(size_t)(r0 + it * 16 + (t >> 4)) * 256 + k0 + (t & 15) * 4];
            #pragma unroll
            for (int it = 0; it < 16; ++it)
                wb_r[it] = *(const float4*)&W[(size_t)(it * 16 + (t >> 4)) * 256 + k0 + (t & 15) * 4];
        }
        #pragma unroll
        for (int kk = 0; kk < 2; ++kk) {
            bf16x8 af[4], bfr[4];
            #pragma unroll
            for (int ri = 0; ri < 4; ++ri)
                af[ri] = *(const bf16x8*)&hA[(ri * 16 + ln) * 72 + kk * 32 + quad * 8];
            #pragma unroll
            for (int oi = 0; oi < 4; ++oi)
                bfr[oi] = *(const bf16x8*)&hB[(w * 64 + oi * 16 + ln) * 72 + kk * 32 + quad * 8];
            #pragma unroll
            for (int ri = 0; ri < 4; ++ri)
                #pragma unroll
                for (int oi = 0; oi < 4; ++oi)
                    acc[ri][oi] = __builtin_amdgcn_mfma_f32_16x16x32_bf16(
                        af[ri], bfr[oi], acc[ri][oi], 0, 0, 0);
        }
        __syncthreads();
    }

    #pragma unroll
    for (int ri = 0; ri < 4; ++ri) {
        const int n = ri * 16 + quad * 4;
        #pragma unroll
        for (int oi = 0; oi < 4; ++oi) {
            const int o = w * 64 + oi * 16 + ln;
            bf16x4 pv = {(__bf16)acc[ri][oi][0], (__bf16)acc[ri][oi][1],
                         (__bf16)acc[ri][oi][2], (__bf16)acc[ri][oi][3]};
            *(bf16x4*)&hB[o * 72 + n] = pv;
        }
    }
    __syncthreads();

    #pragma unroll
    for (int it = 0; it < 8; ++it) {
        const int o   = w * 64 + it * 8 + (l >> 3);
        const int seg = l & 7;
        const bf16x8 v = *(const bf16x8*)&hB[o * 72 + seg * 8];
        *(bf16x8*)&whT[((size_t)b * 256 + o) * 1024 + n0 + seg * 8] = v;
    }

    {
        float s1 = 0.f, s2 = 0.f;
        #pragma unroll 8
        for (int oi = 0; oi < 64; ++oi) {
            const int o = w * 64 + oi;
            const float v = (float)hB[o * 72 + l];
            s1 += v * a_g[o];
            s2 += v * a_g[256 + o];
        }
        red[w * 64 + l]       = s1;
        red[256 + w * 64 + l] = s2;
    }
    __syncthreads();
    if (t < 64) {
        si[b * 1024 + n0 + t] =
            (red[t] + red[64 + t] + red[128 + t] + red[192 + t]) * LOG2E;
    } else if (t < 128) {
        const int n = t - 64;
        sj[b * 1024 + n0 + n] =
            (red[256 + n] + red[320 + n] + red[384 + n] + red[448 + n]) * LOG2E;
    }
}

// ---------------- k3: fused attention (16 waves, 100% occupancy) ------------
// grid 512 (XCD-chunked), 1024 thr (16 waves). 16 j-chunks of 64.
// Wave w: o-slice [w*16, +16). Thread t: S row rowg=t>>4, cols j4*4..+3.
// Body: commit vreg->lds_w; prefetch next whT->vreg; S->lds_s (+ prefetch
// next adj/sj, reload-in-place); __syncthreads; MFMA (setprio); __syncthreads.
__global__ __launch_bounds__(1024, 8) void k3_attn(const int* __restrict__ adj,
                                                   const __bf16* __restrict__ whT,
                                                   const float* __restrict__ si_g,
                                                   const float* __restrict__ sj_g,
                                                   float* __restrict__ out) {
    __shared__ __bf16 lds_w[256 * 72];   // 36 KB whT chunk [o][j_local]
    __shared__ __bf16 lds_s[64 * 72];    // 9 KB S tile
    __shared__ float  lds_denom[64];
    const int t = threadIdx.x;           // 0..1023
    // XCD-chunked swizzle: 512 % 8 == 0 -> bijective; each XCD owns 64
    // consecutive wgids = 4 whole batches, so its whT slice (2 MB) stays in L2.
    const int orig = blockIdx.x;
    const int wgid = (orig & 7) * 64 + (orig >> 3);
    const int b    = wgid >> 4;
    const int i0   = (wgid & 15) << 6;
    const int w    = t >> 6;             // 0..15: wave -> o-slice [w*16,+16)
    const int l    = t & 63;
    const int ln   = l & 15;
    const int quad = l >> 4;
    const int rowg = t >> 4;             // 0..63: S row
    const int j4   = t & 15;             // 0..15
    const int bs   = b * 1024;

    const float si0 = si_g[bs + i0 + rowg];

    float dsum = 0.f;
    f32x4 acc[4] = {};
    const __bf16* whTb = whT + (size_t)b * 256 * 1024;
    const int*    adjb = adj + ((size_t)(bs + i0)) * 1024;

    // staging + prefetch registers (reload-in-place, r1/r8-proven)
    bf16x8 vreg[2];
    int4   a_c;
    float4 sj_c;

    #pragma unroll
    for (int it = 0; it < 2; ++it)
        vreg[it] = *(const bf16x8*)&whTb[(size_t)(it * 128 + (t >> 3)) * 1024 + (t & 7) * 8];
    a_c  = *(const int4*)&adjb[(size_t)rowg * 1024 + j4 * 4];
    sj_c = *(const float4*)&sj_g[bs + j4 * 4];

    for (int jc = 0; jc < 16; ++jc) {
        const int j0 = jc * 64;
        // commit staged whT chunk: 128 rows x 16B per instr, contiguous
        #pragma unroll
        for (int it = 0; it < 2; ++it)
            *(bf16x8*)&lds_w[(it * 128 + (t >> 3)) * 72 + (t & 7) * 8] = vreg[it];
        // prefetch next whT chunk (S-phase + barrier + MFMA as latency cover)
        if (jc < 15) {
            #pragma unroll
            for (int it = 0; it < 2; ++it)
                vreg[it] = *(const bf16x8*)&whTb[
                    (size_t)(it * 128 + (t >> 3)) * 1024 + j0 + 64 + (t & 7) * 8];
        }
        // S: one row, 4 cols. w = adj ? exp2(leakyrelu(si+sj)) : 0
        {
            float e0 = si0 + sj_c.x; e0 = fmaxf(e0, ALPHA * e0);
            float e1 = si0 + sj_c.y; e1 = fmaxf(e1, ALPHA * e1);
            float e2 = si0 + sj_c.z; e2 = fmaxf(e2, ALPHA * e2);
            float e3 = si0 + sj_c.w; e3 = fmaxf(e3, ALPHA * e3);
            const float w0 = a_c.x > 0 ? exp2f(e0) : 0.f;
            const float w1 = a_c.y > 0 ? exp2f(e1) : 0.f;
            const float w2 = a_c.z > 0 ? exp2f(e2) : 0.f;
            const float w3 = a_c.w > 0 ? exp2f(e3) : 0.f;
            bf16x4 pv = {(__bf16)w0, (__bf16)w1, (__bf16)w2, (__bf16)w3};
            dsum += (float)pv[0] + (float)pv[1] + (float)pv[2] + (float)pv[3];
            *(bf16x4*)&lds_s[rowg * 72 + j4 * 4] = pv;
        }
        // prefetch next adj/sj (reload-in-place; consumed next body)
        if (jc < 15) {
            a_c  = *(const int4*)&adjb[(size_t)rowg * 1024 + j0 + 64 + j4 * 4];
            sj_c = *(const float4*)&sj_g[bs + j0 + 64 + j4 * 4];
        }
        __syncthreads();
        // P(64x64) @ Wh(64x256): wave o-slice of 16 -> 8 MFMA
        __builtin_amdgcn_s_setprio(1);
        #pragma unroll
        for (int kk = 0; kk < 2; ++kk) {
            bf16x8 af[4];
            #pragma unroll
            for (int ri = 0; ri < 4; ++ri)
                af[ri] = *(const bf16x8*)&lds_s[(ri * 16 + ln) * 72 + kk * 32 + quad * 8];
            const bf16x8 bfr = *(const bf16x8*)&lds_w[(w * 16 + ln) * 72 + kk * 32 + quad * 8];
            #pragma unroll
            for (int ri = 0; ri < 4; ++ri)
                acc[ri] = __builtin_amdgcn_mfma_f32_16x16x32_bf16(
                    af[ri], bfr, acc[ri], 0, 0, 0);
        }
        __builtin_amdgcn_s_setprio(0);
        __syncthreads();
    }

    // denominator: reduce across the 16 j4 lanes of each row
    {
        float v = dsum;
        v += __shfl_xor(v, 1);
        v += __shfl_xor(v, 2);
        v += __shfl_xor(v, 4);
        v += __shfl_xor(v, 8);
        if (j4 == 0) lds_denom[rowg] = v;
    }
    __syncthreads();
    // epilogue: normalize, ELU, store. C/D: row = ri*16+quad*4+q, col = w*16+ln.
    #pragma unroll
    for (int ri = 0; ri < 4; ++ri) {
        #pragma unroll
        for (int q = 0; q < 4; ++q) {
            const int il = ri * 16 + quad * 4 + q;
            const float dinv = 1.0f / fmaxf(lds_denom[il], 1e-30f);
            const float v = acc[ri][q] * dinv;
            const float r = v > 0.f ? v : __expf(v) - 1.f;
            out[((size_t)(bs + i0 + il)) * 256 + w * 16 + ln] = r;
        }
    }
}

extern "C" void kernel_launch(void* const* d_in, const int* in_sizes, int n_in,
                              void* d_out, int out_size, void* d_ws, size_t ws_size,
                              hipStream_t stream) {
    const float* h   = (const float*)d_in[0];
    const int*   adj = (const int*)d_in[1];
    const float* W   = (const float*)d_in[2];
    const float* a   = (const float*)d_in[3];
    float* out = (float*)d_out;

    __bf16* whT = (__bf16*)d_ws;                              // 16 MiB
    float*  si  = (float*)((char*)d_ws + (size_t)16777216);   // 128 KiB
    float*  sj  = (float*)((char*)d_ws + (size_t)16777216 + 131072);

    k1_gemm1<<<512, 256, 0, stream>>>(h, W, a, whT, si, sj);
    k3_attn<<<512, 1024, 0, stream>>>(adj, whT, si, sj, out);
}

// Round 14
// 249.912 us; speedup vs baseline: 1.1067x; 1.0063x over previous
//
#include <hip/hip_runtime.h>
#include <hip/hip_bf16.h>

// GAT layer: B=32, N=1024, IN_F=OUT_F=256, alpha=0.2
// FINAL (restore of round-8 best-measured kernel, 250.4 us):
//  k1: WhT[b][o][n] = bf16(h @ W^T), MFMA; fused si/sj pre-scaled by log2(e).
//  k3: fused adj-read + masked-softmax attention + PV MFMA + ELU.
//      512 thr / 8 waves per block (wave w owns a 32-wide o-slice); 16 waves/CU.
//      Per j-chunk: commit staged whT -> lds_w; prefetch next whT/adj/sj into
//      registers (latency hidden under S+barrier+MFMA); S -> lds_s;
//      __syncthreads; MFMA (setprio); __syncthreads.
//      XCD-chunked block swizzle keeps each XCD's whT slice (2 MB) in its L2.
// Session evidence (13 rounds): k3 floor ~75 us is structural -- invariant
// under occupancy (8/16/32 waves/CU), barrier discipline (drain vs counted
// vmcnt), dataflow (mask vs raw adj; LDS-staged vs direct whT; S via LDS vs
// registers), and phase scheduling. Timed region is dominated by 157 us of
// harness workspace fills at 85% HBM peak.

#define ALPHA 0.2f
#define LOG2E 1.44269504f

typedef __bf16 bf16x8 __attribute__((ext_vector_type(8)));
typedef __bf16 bf16x4 __attribute__((ext_vector_type(4)));
typedef float  f32x4  __attribute__((ext_vector_type(4)));
typedef unsigned long long u64;

// ---------------- k1: Wh = h @ W^T -> whT (bf16) + si/sj ----------------
// grid 512 x 256 thr; block = 64 n-rows x 256 o, K chunks of 64, reg-prefetched.
__global__ __launch_bounds__(256) void k1_gemm1(const float* __restrict__ h,
                                                const float* __restrict__ W,
                                                const float* __restrict__ a_g,
                                                __bf16* __restrict__ whT,
                                                float* __restrict__ si,
                                                float* __restrict__ sj) {
    __shared__ __bf16 hA[64 * 72];
    __shared__ __bf16 hB[256 * 72];   // W tiles; reused as [o][n] out-staging
    __shared__ float  red[512];
    const int t    = threadIdx.x;
    const int r0   = blockIdx.x * 64;
    const int b    = r0 >> 10;
    const int n0   = r0 & 1023;
    const int w    = t >> 6;
    const int l    = t & 63;
    const int ln   = l & 15;
    const int quad = l >> 4;

    f32x4 acc[4][4] = {};
    float4 ha_r[4], wb_r[16];

    #pragma unroll
    for (int it = 0; it < 4; ++it)
        ha_r[it] = *(const float4*)&h[(size_t)(r0 + it * 16 + (t >> 4)) * 256 + (t & 15) * 4];
    #pragma unroll
    for (int it = 0; it < 16; ++it)
        wb_r[it] = *(const float4*)&W[(size_t)(it * 16 + (t >> 4)) * 256 + (t & 15) * 4];

    for (int kc = 0; kc < 4; ++kc) {
        #pragma unroll
        for (int it = 0; it < 4; ++it) {
            const float4 v = ha_r[it];
            bf16x4 pv = {(__bf16)v.x, (__bf16)v.y, (__bf16)v.z, (__bf16)v.w};
            *(bf16x4*)&hA[(it * 16 + (t >> 4)) * 72 + (t & 15) * 4] = pv;
        }
        #pragma unroll
        for (int it = 0; it < 16; ++it) {
            const float4 v = wb_r[it];
            bf16x4 pv = {(__bf16)v.x, (__bf16)v.y, (__bf16)v.z, (__bf16)v.w};
            *(bf16x4*)&hB[(it * 16 + (t >> 4)) * 72 + (t & 15) * 4] = pv;
        }
        __syncthreads();
        if (kc < 3) {
            const int k0 = (kc + 1) * 64;
            #pragma unroll
            for (int it = 0; it < 4; ++it)
                ha_r[it] = *(const float4*)&h[(size_t)(r0 + it * 16 + (t >> 4)) * 256 + k0 + (t & 15) * 4];
            #pragma unroll
            for (int it = 0; it < 16; ++it)
                wb_r[it] = *(const float4*)&W[(size_t)(it * 16 + (t >> 4)) * 256 + k0 + (t & 15) * 4];
        }
        #pragma unroll
        for (int kk = 0; kk < 2; ++kk) {
            bf16x8 af[4], bfr[4];
            #pragma unroll
            for (int ri = 0; ri < 4; ++ri)
                af[ri] = *(const bf16x8*)&hA[(ri * 16 + ln) * 72 + kk * 32 + quad * 8];
            #pragma unroll
            for (int oi = 0; oi < 4; ++oi)
                bfr[oi] = *(const bf16x8*)&hB[(w * 64 + oi * 16 + ln) * 72 + kk * 32 + quad * 8];
            #pragma unroll
            for (int ri = 0; ri < 4; ++ri)
                #pragma unroll
                for (int oi = 0; oi < 4; ++oi)
                    acc[ri][oi] = __builtin_amdgcn_mfma_f32_16x16x32_bf16(
                        af[ri], bfr[oi], acc[ri][oi], 0, 0, 0);
        }
        __syncthreads();
    }

    #pragma unroll
    for (int ri = 0; ri < 4; ++ri) {
        const int n = ri * 16 + quad * 4;
        #pragma unroll
        for (int oi = 0; oi < 4; ++oi) {
            const int o = w * 64 + oi * 16 + ln;
            bf16x4 pv = {(__bf16)acc[ri][oi][0], (__bf16)acc[ri][oi][1],
                         (__bf16)acc[ri][oi][2], (__bf16)acc[ri][oi][3]};
            *(bf16x4*)&hB[o * 72 + n] = pv;
        }
    }
    __syncthreads();

    #pragma unroll
    for (int it = 0; it < 8; ++it) {
        const int o   = w * 64 + it * 8 + (l >> 3);
        const int seg = l & 7;
        const bf16x8 v = *(const bf16x8*)&hB[o * 72 + seg * 8];
        *(bf16x8*)&whT[((size_t)b * 256 + o) * 1024 + n0 + seg * 8] = v;
    }

    {
        float s1 = 0.f, s2 = 0.f;
        #pragma unroll 8
        for (int oi = 0; oi < 64; ++oi) {
            const int o = w * 64 + oi;
            const float v = (float)hB[o * 72 + l];
            s1 += v * a_g[o];
            s2 += v * a_g[256 + o];
        }
        red[w * 64 + l]       = s1;
        red[256 + w * 64 + l] = s2;
    }
    __syncthreads();
    if (t < 64) {
        si[b * 1024 + n0 + t] =
            (red[t] + red[64 + t] + red[128 + t] + red[192 + t]) * LOG2E;
    } else if (t < 128) {
        const int n = t - 64;
        sj[b * 1024 + n0 + n] =
            (red[256 + n] + red[320 + n] + red[384 + n] + red[448 + n]) * LOG2E;
    }
}

// ---------------- k3: fused attention (8 waves, __syncthreads pipeline) -----
// grid 512 (XCD-chunked), 512 thr (8 waves). 16 j-chunks of 64.
// Wave w: o-range [w*32, w*32+32). Thread t: S rows rowg=t>>4 and rowg+32,
// cols j4*4..+3.
#define K3_BODY(JC, A0C, A1C, SJC, A0N, A1N, SJN)                              \
  {                                                                            \
    const int j0 = (JC) * 64;                                                  \
    /* commit staged whT chunk to LDS */                                       \
    _Pragma("unroll")                                                          \
    for (int it = 0; it < 4; ++it)                                             \
      *(bf16x8*)&lds_w[(it * 64 + (t >> 3)) * 72 + (t & 7) * 8] = vreg[it];    \
    /* prefetch next whT chunk (gets the S-phase as latency cover) */          \
    if ((JC) < 15) {                                                           \
      _Pragma("unroll")                                                        \
      for (int it = 0; it < 4; ++it)                                           \
        vreg[it] = *(const bf16x8*)&whTb[                                      \
            (size_t)(it * 64 + (t >> 3)) * 1024 + j0 + 64 + (t & 7) * 8];      \
      A0N = *(const int4*)&adjb[(size_t)rowg * 1024 + j0 + 64 + j4 * 4];       \
      A1N = *(const int4*)&adjb[(size_t)(rowg + 32) * 1024 + j0 + 64 + j4 * 4];\
      SJN = *(const float4*)&sj_g[bs + j0 + 64 + j4 * 4];                      \
    }                                                                          \
    /* S tile: w = adj ? exp2(leakyrelu(si+sj)) : 0  (si/sj pre-scaled) */     \
    {                                                                          \
      float e0 = si0 + SJC.x; e0 = fmaxf(e0, ALPHA * e0);                      \
      float e1 = si0 + SJC.y; e1 = fmaxf(e1, ALPHA * e1);                      \
      float e2 = si0 + SJC.z; e2 = fmaxf(e2, ALPHA * e2);                      \
      float e3 = si0 + SJC.w; e3 = fmaxf(e3, ALPHA * e3);                      \
      const float w0 = A0C.x > 0 ? exp2f(e0) : 0.f;                            \
      const float w1 = A0C.y > 0 ? exp2f(e1) : 0.f;                            \
      const float w2 = A0C.z > 0 ? exp2f(e2) : 0.f;                            \
      const float w3 = A0C.w > 0 ? exp2f(e3) : 0.f;                            \
      bf16x4 pv = {(__bf16)w0, (__bf16)w1, (__bf16)w2, (__bf16)w3};            \
      dsum0 += (float)pv[0] + (float)pv[1] + (float)pv[2] + (float)pv[3];      \
      *(bf16x4*)&lds_s[rowg * 72 + j4 * 4] = pv;                               \
    }                                                                          \
    {                                                                          \
      float e0 = si1 + SJC.x; e0 = fmaxf(e0, ALPHA * e0);                      \
      float e1 = si1 + SJC.y; e1 = fmaxf(e1, ALPHA * e1);                      \
      float e2 = si1 + SJC.z; e2 = fmaxf(e2, ALPHA * e2);                      \
      float e3 = si1 + SJC.w; e3 = fmaxf(e3, ALPHA * e3);                      \
      const float w0 = A1C.x > 0 ? exp2f(e0) : 0.f;                            \
      const float w1 = A1C.y > 0 ? exp2f(e1) : 0.f;                            \
      const float w2 = A1C.z > 0 ? exp2f(e2) : 0.f;                            \
      const float w3 = A1C.w > 0 ? exp2f(e3) : 0.f;                            \
      bf16x4 pv = {(__bf16)w0, (__bf16)w1, (__bf16)w2, (__bf16)w3};            \
      dsum1 += (float)pv[0] + (float)pv[1] + (float)pv[2] + (float)pv[3];      \
      *(bf16x4*)&lds_s[(rowg + 32) * 72 + j4 * 4] = pv;                        \
    }                                                                          \
    __syncthreads();                                                           \
    /* P(64x64) @ Wh(64x256): wave o-slice of 32 */                            \
    __builtin_amdgcn_s_setprio(1);                                             \
    _Pragma("unroll")                                                          \
    for (int kk = 0; kk < 2; ++kk) {                                           \
      bf16x8 af[4], bfr[2];                                                    \
      _Pragma("unroll")                                                        \
      for (int ri = 0; ri < 4; ++ri)                                           \
        af[ri] = *(const bf16x8*)&lds_s[(ri * 16 + ln) * 72 + kk * 32 + quad * 8]; \
      _Pragma("unroll")                                                        \
      for (int oi = 0; oi < 2; ++oi)                                           \
        bfr[oi] = *(const bf16x8*)&lds_w[(w * 32 + oi * 16 + ln) * 72 + kk * 32 + quad * 8]; \
      _Pragma("unroll")                                                        \
      for (int ri = 0; ri < 4; ++ri)                                           \
        _Pragma("unroll")                                                      \
        for (int oi = 0; oi < 2; ++oi)                                         \
          acc[ri][oi] = __builtin_amdgcn_mfma_f32_16x16x32_bf16(               \
              af[ri], bfr[oi], acc[ri][oi], 0, 0, 0);                          \
    }                                                                          \
    __builtin_amdgcn_s_setprio(0);                                             \
    __syncthreads();                                                           \
  }

__global__ __launch_bounds__(512, 4) void k3_attn(const int* __restrict__ adj,
                                                  const __bf16* __restrict__ whT,
                                                  const float* __restrict__ si_g,
                                                  const float* __restrict__ sj_g,
                                                  float* __restrict__ out) {
    __shared__ __bf16 lds_w[256 * 72];   // 36 KB whT chunk [o][j_local]
    __shared__ __bf16 lds_s[64 * 72];    // 9 KB S tile
    __shared__ float  lds_denom[64];
    const int t = threadIdx.x;           // 0..511
    // XCD-chunked swizzle: 512 % 8 == 0 -> bijective; each XCD owns 64
    // consecutive wgids = 4 whole batches, so its whT slice (2 MB) stays in L2.
    const int orig = blockIdx.x;
    const int wgid = (orig & 7) * 64 + (orig >> 3);
    const int b    = wgid >> 4;
    const int i0   = (wgid & 15) << 6;
    const int w    = t >> 6;             // 0..7
    const int l    = t & 63;
    const int ln   = l & 15;
    const int quad = l >> 4;
    const int rowg = t >> 4;             // 0..31 (S row pair: rowg, rowg+32)
    const int j4   = t & 15;             // 0..15
    const int bs   = b * 1024;

    const float si0 = si_g[bs + i0 + rowg];
    const float si1 = si_g[bs + i0 + rowg + 32];

    float dsum0 = 0.f, dsum1 = 0.f;
    f32x4 acc[4][2] = {};
    const __bf16* whTb = whT + (size_t)b * 256 * 1024;
    const int*    adjb = adj + ((size_t)(bs + i0)) * 1024;

    // staging + prefetch registers (static names, c/n rotation for adj/sj)
    bf16x8 vreg[4];
    int4   a0_c, a1_c, a0_n, a1_n;
    float4 sj_c, sj_n;

    #pragma unroll
    for (int it = 0; it < 4; ++it)
        vreg[it] = *(const bf16x8*)&whTb[(size_t)(it * 64 + (t >> 3)) * 1024 + (t & 7) * 8];
    a0_c = *(const int4*)&adjb[(size_t)rowg * 1024 + j4 * 4];
    a1_c = *(const int4*)&adjb[(size_t)(rowg + 32) * 1024 + j4 * 4];
    sj_c = *(const float4*)&sj_g[bs + j4 * 4];

    for (int jj = 0; jj < 8; ++jj) {
        K3_BODY(2 * jj,     a0_c, a1_c, sj_c, a0_n, a1_n, sj_n);
        K3_BODY(2 * jj + 1, a0_n, a1_n, sj_n, a0_c, a1_c, sj_c);
    }

    // reduce denominators across the 16 j4 lanes per row
    {
        float v = dsum0;
        v += __shfl_xor(v, 1);
        v += __shfl_xor(v, 2);
        v += __shfl_xor(v, 4);
        v += __shfl_xor(v, 8);
        if (j4 == 0) lds_denom[rowg] = v;
        float u = dsum1;
        u += __shfl_xor(u, 1);
        u += __shfl_xor(u, 2);
        u += __shfl_xor(u, 4);
        u += __shfl_xor(u, 8);
        if (j4 == 0) lds_denom[rowg + 32] = u;
    }
    __syncthreads();
    // epilogue: normalize, ELU, store
    #pragma unroll
    for (int ri = 0; ri < 4; ++ri) {
        #pragma unroll
        for (int q = 0; q < 4; ++q) {
            const int il = ri * 16 + quad * 4 + q;
            const float dinv = 1.0f / fmaxf(lds_denom[il], 1e-30f);
            #pragma unroll
            for (int oi = 0; oi < 2; ++oi) {
                const int o = w * 32 + oi * 16 + ln;
                const float v = acc[ri][oi][q] * dinv;
                const float r = v > 0.f ? v : __expf(v) - 1.f;
                out[((size_t)(bs + i0 + il)) * 256 + o] = r;
            }
        }
    }
}

extern "C" void kernel_launch(void* const* d_in, const int* in_sizes, int n_in,
                              void* d_out, int out_size, void* d_ws, size_t ws_size,
                              hipStream_t stream) {
    const float* h   = (const float*)d_in[0];
    const int*   adj = (const int*)d_in[1];
    const float* W   = (const float*)d_in[2];
    const float* a   = (const float*)d_in[3];
    float* out = (float*)d_out;

    __bf16* whT = (__bf16*)d_ws;                              // 16 MiB
    float*  si  = (float*)((char*)d_ws + (size_t)16777216);   // 128 KiB
    float*  sj  = (float*)((char*)d_ws + (size_t)16777216 + 131072);

    k1_gemm1<<<512, 256, 0, stream>>>(h, W, a, whT, si, sj);
    k3_attn<<<512, 512, 0, stream>>>(adj, whT, si, sj, out);
}